// Round 11
// baseline (1208.684 us; speedup 1.0000x reference)
//
#include <hip/hip_runtime.h>

// cRNN: B=512, T=2048, I=4, H=100, O=1
// h_t = tanh(W_ih x_t + W_hh h_{t-1});  out[b,t] = W_fc.h_t + b_fc
// One block (256 thr, 4 waves) per chain; 4-way K-SPLIT: wave w owns
// k in [25w, 25w+25). Each lane owns rows (lane, lane+64) -> 50 weight VGPRs,
// each readlane feeds 2 FMAs. Per step: partial float2 write + 1 barrier +
// 4 float2 reads (contiguous, conflict-free); every wave rebuilds the h it
// needs in registers via its own tanh (h replicated in-wave, no h broadcast).
// 2048 waves total = 2 waves/SIMD (different chains) -> mutual stall hiding.
// Defensive rev of r9: chunk-end barrier restored, pab zero-initialized.

#define BB 512
#define TT 2048
#define II 4
#define HH 100
#define KQ 25               // k-quarter per wave
#define HP 112              // history row stride (float4-aligned, pads zeroed)
#define CHUNK 64
#define NCH (TT / CHUNK)

__device__ __forceinline__ float rlf(float v, int l) {
    return __int_as_float(__builtin_amdgcn_readlane(__float_as_int(v), l));
}

__global__ __launch_bounds__(256, 1) void crnn_kernel(
    const float* __restrict__ x,     // [B,T,I]
    const float* __restrict__ W_ih,  // [H,I]
    const float* __restrict__ W_hh,  // [H,H]
    const float* __restrict__ W_fc,  // [1,H]
    const float* __restrict__ b_fc,  // [1]
    float* __restrict__ out)         // [B,T]
{
    __shared__ __align__(16) float  xs[TT * II];     // 32 KB staged input
    __shared__ __align__(16) float  hh[CHUNK * HP];  // 28 KB h history
    __shared__ __align__(16) float  wfcs[HP];
    __shared__ __align__(16) float2 pab[2][4][64];   // [parity][wave][lane]
    __shared__ __align__(16) float  pt[4][CHUNK];

    const int tid  = threadIdx.x;
    const int b    = blockIdx.x;
    const int lane = tid & 63;
    const int w    = tid >> 6;
    const int rA   = lane;                                  // row A
    const int rB   = (lane < HH - 64) ? (64 + lane) : (HH - 1);  // row B (clamped)

    // ---- stage x[b] into LDS (coalesced float4) ----
    const float4* xg = reinterpret_cast<const float4*>(x + (size_t)b * TT * II);
    float4* xl = reinterpret_cast<float4*>(xs);
#pragma unroll
    for (int it = 0; it < (TT * II / 4) / 256; ++it)
        xl[it * 256 + tid] = xg[it * 256 + tid];

    // ---- weights: this wave's k-quarter of rows rA, rB ----
    float wA[KQ], wB[KQ];
    {
        const float* pa = W_hh + rA * HH + w * KQ;
        const float* pb = W_hh + rB * HH + w * KQ;
#pragma unroll
        for (int i = 0; i < KQ; ++i) { wA[i] = pa[i]; wB[i] = pb[i]; }
    }
    float4 wihA = make_float4(0.f, 0.f, 0.f, 0.f);
    float4 wihB = make_float4(0.f, 0.f, 0.f, 0.f);
    if (w == 0) {
        wihA = reinterpret_cast<const float4*>(W_ih)[rA];
        wihB = reinterpret_cast<const float4*>(W_ih)[rB];
    }
    if (tid < HP) wfcs[tid] = (tid < HH) ? W_fc[tid] : 0.f;
    const float bias = b_fc[0];
    // zero history pad columns (HH..HP-1) and pab once
    for (int i = tid; i < CHUNK * (HP - HH); i += 256) {
        int r = i / (HP - HH), p = i % (HP - HH);
        hh[r * HP + HH + p] = 0.f;
    }
    pab[0][w][lane] = make_float2(0.f, 0.f);
    pab[1][w][lane] = make_float2(0.f, 0.f);
    __syncthreads();

    float vh = 0.f, vh2 = 0.f;             // replicated h halves (h_0 = 0)
    float* outb = out + (size_t)b * TT;
    const float4* xs4 = reinterpret_cast<const float4*>(xs);
    float4 xv = make_float4(0.f, 0.f, 0.f, 0.f);
    if (w == 0) xv = xs4[0];               // rolling 1-step x prefetch

    for (int c = 0; c < NCH; ++c) {
#pragma unroll 1
        for (int s = 0; s < CHUNK; ++s) {
            float aA0 = 0.f, aA1 = 0.f, aB0 = 0.f, aB1 = 0.f;

            if (w == 0) {
                // xp + k = 0..24 from vh
                aA0 = fmaf(wihA.z, xv.z, wihA.x * xv.x);
                aA1 = fmaf(wihA.w, xv.w, wihA.y * xv.y);
                aB0 = fmaf(wihB.z, xv.z, wihB.x * xv.x);
                aB1 = fmaf(wihB.w, xv.w, wihB.y * xv.y);
#pragma unroll
                for (int i = 0; i < 24; i += 2) {
                    float h0 = rlf(vh, i), h1 = rlf(vh, i + 1);
                    aA0 = fmaf(wA[i],     h0, aA0);  aB0 = fmaf(wB[i],     h0, aB0);
                    aA1 = fmaf(wA[i + 1], h1, aA1);  aB1 = fmaf(wB[i + 1], h1, aB1);
                }
                { float h0 = rlf(vh, 24);
                  aA0 = fmaf(wA[24], h0, aA0);  aB0 = fmaf(wB[24], h0, aB0); }
            } else if (w == 1) {
                // k = 25..49 from vh
#pragma unroll
                for (int i = 0; i < 24; i += 2) {
                    float h0 = rlf(vh, 25 + i), h1 = rlf(vh, 26 + i);
                    aA0 = fmaf(wA[i],     h0, aA0);  aB0 = fmaf(wB[i],     h0, aB0);
                    aA1 = fmaf(wA[i + 1], h1, aA1);  aB1 = fmaf(wB[i + 1], h1, aB1);
                }
                { float h0 = rlf(vh, 49);
                  aA0 = fmaf(wA[24], h0, aA0);  aB0 = fmaf(wB[24], h0, aB0); }
            } else if (w == 2) {
                // k = 50..63 from vh, k = 64..74 from vh2 (lanes 0..10)
#pragma unroll
                for (int i = 0; i < 14; i += 2) {
                    float h0 = rlf(vh, 50 + i), h1 = rlf(vh, 51 + i);
                    aA0 = fmaf(wA[i],     h0, aA0);  aB0 = fmaf(wB[i],     h0, aB0);
                    aA1 = fmaf(wA[i + 1], h1, aA1);  aB1 = fmaf(wB[i + 1], h1, aB1);
                }
#pragma unroll
                for (int i = 14; i < 24; i += 2) {
                    float h0 = rlf(vh2, i - 14), h1 = rlf(vh2, i - 13);
                    aA0 = fmaf(wA[i],     h0, aA0);  aB0 = fmaf(wB[i],     h0, aB0);
                    aA1 = fmaf(wA[i + 1], h1, aA1);  aB1 = fmaf(wB[i + 1], h1, aB1);
                }
                { float h0 = rlf(vh2, 10);
                  aA0 = fmaf(wA[24], h0, aA0);  aB0 = fmaf(wB[24], h0, aB0); }
            } else {
                // k = 75..99 from vh2 (lanes 11..35)
#pragma unroll
                for (int i = 0; i < 24; i += 2) {
                    float h0 = rlf(vh2, 11 + i), h1 = rlf(vh2, 12 + i);
                    aA0 = fmaf(wA[i],     h0, aA0);  aB0 = fmaf(wB[i],     h0, aB0);
                    aA1 = fmaf(wA[i + 1], h1, aA1);  aB1 = fmaf(wB[i + 1], h1, aB1);
                }
                { float h0 = rlf(vh2, 35);
                  aA0 = fmaf(wA[24], h0, aA0);  aB0 = fmaf(wB[24], h0, aB0); }
            }

            // roll the x prefetch (latency hides under barrier/exchange)
            {
                int g = c * CHUNK + s + 1;
                if (w == 0 && g < TT) xv = xs4[g];
            }

            // ---- partial exchange (parity-double-buffered, 1 barrier) ----
            const int par = s & 1;
            pab[par][w][lane] = make_float2(aA0 + aA1, aB0 + aB1);
            __syncthreads();
            float2 p0 = pab[par][0][lane];
            float2 p1 = pab[par][1][lane];
            float2 p2 = pab[par][2][lane];
            float2 p3 = pab[par][3][lane];
            float sA = (p0.x + p1.x) + (p2.x + p3.x);
            float sB = (p0.y + p1.y) + (p2.y + p3.y);

            // tanh only for the halves this wave consumes/stores
            if (w < 2) {
                float e = __expf(2.f * sA);
                vh = 1.f - 2.f * __builtin_amdgcn_rcpf(e + 1.f);
                if (w == 0) hh[s * HP + lane] = vh;
            } else if (w == 2) {
                float eA = __expf(2.f * sA);
                float eB = __expf(2.f * sB);
                vh  = 1.f - 2.f * __builtin_amdgcn_rcpf(eA + 1.f);
                vh2 = 1.f - 2.f * __builtin_amdgcn_rcpf(eB + 1.f);
                if (lane < HH - 64) hh[s * HP + 64 + lane] = vh2;
            } else {
                float e = __expf(2.f * sB);
                vh2 = 1.f - 2.f * __builtin_amdgcn_rcpf(e + 1.f);
            }
        }

        // ---- amortized output projection over the 64-row history ----
        __syncthreads();                       // step-63 history writes visible
        const int tl = tid & 63;
        const int kq = tid >> 6;               // k-quarter of 28 (pads zeroed)
        const float4* wf4 = reinterpret_cast<const float4*>(wfcs + kq * 28);
        const float4* hr  = reinterpret_cast<const float4*>(hh + tl * HP + kq * 28);
        float csum = 0.f;
#pragma unroll
        for (int i = 0; i < 7; ++i) {
            float4 hv = hr[i], wv = wf4[i];
            csum = fmaf(hv.x, wv.x, csum);
            csum = fmaf(hv.y, wv.y, csum);
            csum = fmaf(hv.z, wv.z, csum);
            csum = fmaf(hv.w, wv.w, csum);
        }
        pt[kq][tl] = csum;
        __syncthreads();
        if (tid < CHUNK)
            outb[c * CHUNK + tid] =
                ((pt[0][tid] + pt[1][tid]) + (pt[2][tid] + pt[3][tid])) + bias;
        __syncthreads();                       // defensive: order out/pt reads
    }                                          // before next chunk's hh writes
}

extern "C" void kernel_launch(void* const* d_in, const int* in_sizes, int n_in,
                              void* d_out, int out_size, void* d_ws, size_t ws_size,
                              hipStream_t stream) {
    const float* x    = (const float*)d_in[0];
    const float* W_ih = (const float*)d_in[1];
    const float* W_hh = (const float*)d_in[2];
    const float* W_fc = (const float*)d_in[3];
    const float* b_fc = (const float*)d_in[4];
    float* out = (float*)d_out;
    crnn_kernel<<<BB, 256, 0, stream>>>(x, W_ih, W_hh, W_fc, b_fc, out);
}